// Round 11
// baseline (182.681 us; speedup 1.0000x reference)
//
#include <hip/hip_runtime.h>
#include <hip/hip_bf16.h>

#define NHEADS 16
#define HDIM   64
#define HID    1024
#define BB     4
#define SS     4096
#define MM     (BB*SS)      // 16384 rows
#define KK     HID          // 1024
#define NN     (2*HID)      // 2048 cols (Q | K)

using short8 = __attribute__((ext_vector_type(8))) short;
using f32x4  = __attribute__((ext_vector_type(4))) float;

__device__ __forceinline__ float bf2f(ushort u) {
  return __uint_as_float(((unsigned)u) << 16);
}
__device__ __forceinline__ ushort f2bf(float f) {
  unsigned u = __float_as_uint(f);
  unsigned r = (u + 0x7fffu + ((u >> 16) & 1u)) >> 16;  // RNE
  return (ushort)r;
}

__device__ __forceinline__ void gload16(const void* g, void* l) {
  __builtin_amdgcn_global_load_lds(
      (const __attribute__((address_space(1))) void*)g,
      (__attribute__((address_space(3))) void*)l, 16, 0, 0);
}

// ---------------------------------------------------------------- cast hs->bf16
__global__ __launch_bounds__(256) void cast_hs_k(const float* __restrict__ in,
                                                 ushort* __restrict__ out) {
  size_t i = ((size_t)blockIdx.x * 256 + threadIdx.x) * 8;
  float4 a = *(const float4*)(in + i);
  float4 b = *(const float4*)(in + i + 4);
  ushort r[8];
  r[0]=f2bf(a.x); r[1]=f2bf(a.y); r[2]=f2bf(a.z); r[3]=f2bf(a.w);
  r[4]=f2bf(b.x); r[5]=f2bf(b.y); r[6]=f2bf(b.z); r[7]=f2bf(b.w);
  *(uint4*)(out + i) = *(const uint4*)r;
}

// ------------------------------------------- W (K,N) -> Bt (N,K) bf16, Wq|Wkv fused
__global__ __launch_bounds__(256) void wcast_k(const float* __restrict__ Wq,
                                               const float* __restrict__ Wkv,
                                               ushort* __restrict__ Bt) {
  __shared__ float tile[32][33];
  int k0 = blockIdx.x * 32, n0 = blockIdx.y * 32;
  int tx = threadIdx.x, ty = threadIdx.y;
  const float* src = (n0 < HID) ? Wq : Wkv;
  int nc = (n0 < HID) ? n0 : n0 - HID;
#pragma unroll
  for (int j = 0; j < 4; ++j)
    tile[ty + 8*j][tx] = src[(size_t)(k0 + ty + 8*j) * HID + nc + tx];
  __syncthreads();
#pragma unroll
  for (int j = 0; j < 4; ++j)
    Bt[(size_t)(n0 + ty + 8*j) * KK + k0 + tx] = f2bf(tile[tx][ty + 8*j]);
}

// ---------------------------------------------------------------- fused QK GEMM
// 128x128 tile, BK=64, 256 threads (4 waves 2x2, wave tile 64x64, acc=64 VGPR),
// 64KB LDS double-buffer -> TWO independent blocks per CU (launch_bounds(256,2);
// LDS 160/64 = 2). Mechanism under test: inter-block overlap (m114) — while one
// block drains vmcnt/barrier, the other block's waves issue MFMA. All staging/
// swizzle geometry is the R2-verified scheme (128B rows, chunk^(row&7), 0
// measured conflicts). Direct swapped-operand epilogue (R3-verified).
// LDS map: buf b at b*32768: A 16KB at +0, B 16KB at +16384.
__global__ __launch_bounds__(256, 2) void gemm_k(const ushort* __restrict__ A,
                                                 const ushort* __restrict__ Bt,
                                                 const float* __restrict__ bq,
                                                 const float* __restrict__ bkv,
                                                 ushort* __restrict__ C) {
  extern __shared__ char lds_c[];
  const int tid = threadIdx.x;
  const int bid = blockIdx.x;
  const int wg = (bid & 7) * 256 + (bid >> 3);   // XCD swizzle (2048 % 8 == 0)
  const int tm = wg >> 4, tn = wg & 15;          // 128 x 16 tiles
  const int w = tid >> 6, lane = tid & 63;
  const int wr = w >> 1, wc = w & 1;
  const int lr = lane & 15, hi = lane >> 4;

  const ushort* Ab = A  + (size_t)tm * 128 * KK;
  const ushort* Bb = Bt + (size_t)tn * 128 * KK;

  // staging: region = 16KB = 128 rows x 8 chunks(16B); slot i covers bytes
  // [i*4096,(i+1)*4096): thread t -> o = i*4096 + t*16, row=o>>7, chunk=(o>>4)&7.
  // Global source pre-swizzled: chunk_g = chunk ^ (row&7)  (rule #21 involution).
  int srow[4], scol[4];
#pragma unroll
  for (int i = 0; i < 4; ++i) {
    int o = i * 4096 + tid * 16;
    int row = o >> 7, ch = (o >> 4) & 7;
    srow[i] = row;
    scol[i] = ((ch ^ (row & 7)) << 3);   // ushort offset within row
  }

  // fragment reads: row low bits = lr&7 for all m/n
  const int aoff0 = (wr * 64 + lr) * 128;   // byte offset of m=0 row in A region
  const int boff0 = (wc * 64 + lr) * 128;
  const int r7 = lr & 7;

  f32x4 acc[4][4];
#pragma unroll
  for (int m = 0; m < 4; ++m)
#pragma unroll
    for (int n = 0; n < 4; ++n) acc[m][n] = (f32x4){0.f, 0.f, 0.f, 0.f};
  short8 bfrag[4];

#define STGALL(T1, DSTB)                                                        \
  {                                                                             \
    _Pragma("unroll") for (int i = 0; i < 4; ++i)                               \
      gload16(Ab + (T1) * 64 + (size_t)srow[i] * KK + scol[i],                  \
              lds_c + (DSTB) + i * 4096 + tid * 16);                            \
    _Pragma("unroll") for (int i = 0; i < 4; ++i)                               \
      gload16(Bb + (T1) * 64 + (size_t)srow[i] * KK + scol[i],                  \
              lds_c + (DSTB) + 16384 + i * 4096 + tid * 16);                    \
  }

#define LOADB(BBASE, CB)                                                        \
  _Pragma("unroll") for (int n = 0; n < 4; ++n)                                 \
    bfrag[n] = *(const short8*)(lds_c + (BBASE) + boff0 + n * 2048 +            \
                                ((((CB) + hi) ^ r7) << 4));

#define WAITV(N)                                                                \
  { asm volatile("s_waitcnt vmcnt(" #N ")" ::: "memory");                       \
    __builtin_amdgcn_sched_barrier(0); }

#define PH(ABASE, CB, STAGE_CODE, TAIL_CODE)                                    \
  {                                                                             \
    short8 afrag[4];                                                            \
    _Pragma("unroll") for (int m = 0; m < 4; ++m)                               \
      afrag[m] = *(const short8*)(lds_c + (ABASE) + aoff0 + m * 2048 +          \
                                  ((((CB) + hi) ^ r7) << 4));                   \
    STAGE_CODE;                                                                 \
    __builtin_amdgcn_s_barrier();                                               \
    __builtin_amdgcn_sched_barrier(0);                                          \
    __builtin_amdgcn_s_setprio(1);                                              \
    _Pragma("unroll") for (int m = 0; m < 4; ++m)                               \
      _Pragma("unroll") for (int n = 0; n < 4; ++n)                             \
        acc[m][n] = __builtin_amdgcn_mfma_f32_16x16x32_bf16(                    \
            bfrag[n], afrag[m], acc[m][n], 0, 0, 0);                            \
    __builtin_amdgcn_s_setprio(0);                                              \
    TAIL_CODE;                                                                  \
    __builtin_amdgcn_s_barrier();                                               \
    asm volatile("" ::: "memory");                                              \
  }

  // ---- prologue: tile0 -> buf0
  STGALL(0, 0)
  WAITV(0)
  __builtin_amdgcn_s_barrier();
  asm volatile("" ::: "memory");

  // ---- main loop: tile t in buf[t&1]; p1 stages tile t+1 into buf[~t&1]
  // (vacated at end of tile t-1); p2 tail vmcnt(0) (>=1-phase flight) + barrier.
#pragma unroll 1
  for (int t = 0; t < 15; ++t) {
    const int cur = (t & 1) << 15;
    const int alt = cur ^ 32768;
    LOADB(cur + 16384, 0)
    PH(cur, 0, STGALL(t + 1, alt), {})
    LOADB(cur + 16384, 4)
    PH(cur, 4, {}, WAITV(0))
  }
  // final tile (t=15) in buf1, no staging
  LOADB(32768 + 16384, 0)
  PH(32768, 0, {}, {})
  LOADB(32768 + 16384, 4)
  PH(32768, 4, {}, {})

#undef PH
#undef WAITV
#undef LOADB
#undef STGALL

  // ---- epilogue: lane holds C[row = wr*64+m*16+lr][col = wc*64+n*16+hi*4+t]
  const int colb = tn * 128 + wc * 64;
  float4 bv[4];
#pragma unroll
  for (int n = 0; n < 4; ++n) {
    int cg = colb + n * 16 + hi * 4;
    const float* bias = (cg < HID) ? (bq + cg) : (bkv + cg - HID);
    bv[n] = *(const float4*)bias;
  }

#pragma unroll
  for (int m = 0; m < 4; ++m) {
    size_t row = (size_t)tm * 128 + wr * 64 + m * 16 + lr;
    ushort* cp = C + row * NN + colb + hi * 4;
#pragma unroll
    for (int n = 0; n < 4; ++n) {
      unsigned p0 = (unsigned)f2bf(acc[m][n][0] + bv[n].x) |
                    ((unsigned)f2bf(acc[m][n][1] + bv[n].y) << 16);
      unsigned p1 = (unsigned)f2bf(acc[m][n][2] + bv[n].z) |
                    ((unsigned)f2bf(acc[m][n][3] + bv[n].w) << 16);
      uint2 st; st.x = p0; st.y = p1;
      *(uint2*)(cp + n * 16) = st;
    }
  }
}

// ------------------------------------------------- global attention, split-K flash
#define GCH 8
#define GCS (SS / GCH)  // 512

__global__ __launch_bounds__(512) void gattn_part_k(const ushort* __restrict__ QK,
                                                    const float* __restrict__ mask,
                                                    float* __restrict__ P) {
  const int bh = blockIdx.x >> 3, c = blockIdx.x & 7;
  const int b = bh >> 4, h = bh & 15;
  const int tid = threadIdx.x, w = tid >> 6, lane = tid & 63;
  __shared__ float sc[GCS];
  __shared__ float red[8];
  __shared__ float vacc[8][64];

  const float gq = bf2f(QK[(size_t)b * SS * NN + h * HDIM + lane]);  // Q row s=0
  const int s0 = c * GCS;
  float mx = -1e30f;
  for (int s = w; s < GCS; s += 8) {
    float kv = bf2f(QK[((size_t)b * SS + s0 + s) * NN + HID + h * HDIM + lane]);
    float p = gq * kv;
#pragma unroll
    for (int o = 32; o; o >>= 1) p += __shfl_xor(p, o, 64);
    p = p * 0.125f + mask[b * SS + s0 + s];
    if (lane == 0) sc[s] = p;
    mx = fmaxf(mx, p);
  }
  if (lane == 0) red[w] = mx;
  __syncthreads();
  float bm = -1e30f;
#pragma unroll
  for (int i = 0; i < 8; ++i) bm = fmaxf(bm, red[i]);
  __syncthreads();
  float ls = 0.f;
  for (int s = tid; s < GCS; s += 512) {
    float e = __expf(sc[s] - bm);
    sc[s] = e;
    ls += e;
  }
#pragma unroll
  for (int o = 32; o; o >>= 1) ls += __shfl_xor(ls, o, 64);
  if (lane == 0) red[w] = ls;
  __syncthreads();
  float tot = 0.f;
#pragma unroll
  for (int i = 0; i < 8; ++i) tot += red[i];

  float a = 0.f;
  for (int s = w; s < GCS; s += 8)
    a += sc[s] * bf2f(QK[((size_t)b * SS + s0 + s) * NN + HID + h * HDIM + lane]);
  vacc[w][lane] = a;
  __syncthreads();
  if (w == 0) {
    float v = 0.f;
#pragma unroll
    for (int i = 0; i < 8; ++i) v += vacc[i][lane];
    P[1024 + (bh * 8 + c) * 64 + lane] = v;
    if (lane == 0) {
      P[bh * 8 + c] = bm;
      P[512 + bh * 8 + c] = tot;
    }
  }
}

__global__ __launch_bounds__(64) void gattn_comb_k(const float* __restrict__ P,
                                                   float* __restrict__ ctx,
                                                   float* __restrict__ gvec) {
  const int bh = blockIdx.x, b = bh >> 4, h = bh & 15;
  const int lane = threadIdx.x;
  float pm[8];
  float m = -1e30f;
#pragma unroll
  for (int c = 0; c < 8; ++c) { pm[c] = P[bh * 8 + c]; m = fmaxf(m, pm[c]); }
  float tot = 0.f, g = 0.f;
#pragma unroll
  for (int c = 0; c < 8; ++c) {
    float e = __expf(pm[c] - m);
    tot += P[512 + bh * 8 + c] * e;
    g += P[1024 + (bh * 8 + c) * 64 + lane] * e;
  }
  g /= tot;
  gvec[b * HID + h * HDIM + lane] = g;
  ctx[(size_t)b * SS * HID + h * HDIM + lane] = g;
}

// ------------------------------------------------- local attention (4 keys/pos)
// v2 (grid FIXED to BB*256): each wave handles 4 consecutive positions; K rows
// sb-1..sb+4 loaded once into regs and shared (kp/kn = neighbors' ks) ->
// K logical reads 3/pos -> 1.5/pos; gvec hoisted per wave.
__device__ __forceinline__ void unpack16(const ushort* __restrict__ p, float* f) {
  uint4 v0 = *(const uint4*)p;
  uint4 v1 = *(const uint4*)(p + 8);
  unsigned u[8] = {v0.x, v0.y, v0.z, v0.w, v1.x, v1.y, v1.z, v1.w};
#pragma unroll
  for (int i = 0; i < 8; ++i) {
    f[2*i]   = __uint_as_float(u[i] << 16);
    f[2*i+1] = __uint_as_float(u[i] & 0xffff0000u);
  }
}

__global__ __launch_bounds__(256) void local_attn_k(const ushort* __restrict__ QK,
                                                    const float* __restrict__ gvec,
                                                    float* __restrict__ out) {
  const int blk = blockIdx.x;
  const int b = blk >> 8;                         // grid = BB*256
  const int sb = 1 + ((blk & 255) << 4) + ((int)(threadIdx.x >> 6) << 2);
  const int lane = threadIdx.x & 63;
  const int g = lane >> 2, j = lane & 3;
  const int db = g * HDIM + j * 16;

  float gv[16];
  const float* gvp = gvec + b * HID + db;
#pragma unroll
  for (int t = 0; t < 16; t += 4) *(float4*)(gv + t) = *(const float4*)(gvp + t);

  // K rows sb-1 .. sb+4 (rows >= SS wrap to 0; row SS+1 unused)
  float kr[6][16];
#pragma unroll
  for (int i = 0; i < 6; ++i) {
    int R = sb - 1 + i;
    if (R >= SS) R = 0;
    unpack16(QK + ((size_t)b * SS + R) * NN + HID + db, kr[i]);
  }

#pragma unroll
  for (int p = 0; p < 4; ++p) {
    const int s = sb + p;
    if (s >= SS) break;
    float q[16];
    unpack16(QK + ((size_t)b * SS + s) * NN + db, q);

    float d0 = 0.f, d1 = 0.f, d2 = 0.f, d3 = 0.f;
#pragma unroll
    for (int t = 0; t < 16; ++t) {
      d0 += q[t] * kr[p + 1][t];   // k_self
      d1 += q[t] * gv[t];          // k_glob
      d2 += q[t] * kr[p][t];       // k_prev
      d3 += q[t] * kr[p + 2][t];   // k_next
    }
    d0 += __shfl_xor(d0, 1, 64); d0 += __shfl_xor(d0, 2, 64);
    d1 += __shfl_xor(d1, 1, 64); d1 += __shfl_xor(d1, 2, 64);
    d2 += __shfl_xor(d2, 1, 64); d2 += __shfl_xor(d2, 2, 64);
    d3 += __shfl_xor(d3, 1, 64); d3 += __shfl_xor(d3, 2, 64);

    float s0 = d0 * 0.125f, s1 = d1 * 0.125f, s2 = d2 * 0.125f, s3 = d3 * 0.125f;
    float m = fmaxf(fmaxf(s0, s1), fmaxf(s2, s3));
    float e0 = __expf(s0 - m), e1 = __expf(s1 - m);
    float e2 = __expf(s2 - m), e3 = __expf(s3 - m);
    float inv = 1.f / (e0 + e1 + e2 + e3);
    float a0 = e0 * inv, a1 = e1 * inv, a2 = e2 * inv, a3 = e3 * inv;

    float o[16];
#pragma unroll
    for (int t = 0; t < 16; ++t)
      o[t] = a0 * kr[p + 1][t] + a1 * gv[t] + a2 * kr[p][t] + a3 * kr[p + 2][t];
    float* cp = out + ((size_t)b * SS + s) * HID + db;
#pragma unroll
    for (int t = 0; t < 16; t += 4) *(float4*)(cp + t) = *(const float4*)(o + t);

    if (j == 0) {
      float4 av; av.x = a0; av.y = a1; av.z = a2; av.w = a3;
      *(float4*)(out + (size_t)BB * SS * HID +
                 (((size_t)b * NHEADS + g) * (SS - 1) + (s - 1)) * 4) = av;
    }
  }
}

// ---------------------------------------------------------------------- launch
extern "C" void kernel_launch(void* const* d_in, const int* in_sizes, int n_in,
                              void* d_out, int out_size, void* d_ws, size_t ws_size,
                              hipStream_t stream) {
  const float* hs   = (const float*)d_in[0];
  const float* mask = (const float*)d_in[1];
  const float* Wq   = (const float*)d_in[2];
  const float* bq   = (const float*)d_in[3];
  const float* Wkv  = (const float*)d_in[4];
  const float* bkv  = (const float*)d_in[5];
  float* out = (float*)d_out;

  char* ws = (char*)d_ws;
  ushort* hsb  = (ushort*)ws;                                   // 32 MB
  ushort* Bt   = (ushort*)(ws + 33554432);                      // 4 MB
  ushort* QK   = (ushort*)(ws + 33554432 + 4194304);            // 64 MB
  float*  gvec = (float*)(ws + 33554432 + 4194304 + 67108864);  // 16 KB
  float*  P    = (float*)(ws + 33554432 + 4194304 + 67108864 + 16384);  // ~140 KB

  cast_hs_k<<<MM*KK/(256*8), 256, 0, stream>>>(hs, hsb);
  wcast_k<<<dim3(KK/32, NN/32), dim3(32, 8), 0, stream>>>(Wq, Wkv, Bt);
  gemm_k<<<dim3((MM/128)*(NN/128)), dim3(256), 65536, stream>>>(hsb, Bt, bq, bkv, QK);
  gattn_part_k<<<BB*NHEADS*GCH, 512, 0, stream>>>(QK, mask, P);
  gattn_comb_k<<<BB*NHEADS, 64, 0, stream>>>(P, out, gvec);
  local_attn_k<<<BB*256, 256, 0, stream>>>(QK, gvec, out);
}